// Round 1
// 399.682 us; speedup vs baseline: 1.0091x; 1.0091x over previous
//
#include <hip/hip_runtime.h>

#define HC 256   // H*C_H

typedef _Float16 f16x8 __attribute__((ext_vector_type(8)));
typedef float f32x4 __attribute__((ext_vector_type(4)));

union h4u { ushort4 u; _Float16 h[4]; };
union h8u { uint4 u; f16x8 h; };

__device__ __forceinline__ float wave_sum(float v) {
    #pragma unroll
    for (int off = 32; off; off >>= 1) v += __shfl_xor(v, off);
    return v;
}
__device__ __forceinline__ float wave_max(float v) {
    #pragma unroll
    for (int off = 32; off; off >>= 1) v = fmaxf(v, __shfl_xor(v, off));
    return v;
}

// async global->LDS DMA, 16B per lane (global_load_lds_dwordx4)
__device__ __forceinline__ void async16(_Float16* l, const _Float16* gp) {
    __builtin_amdgcn_global_load_lds(
        (const __attribute__((address_space(1))) void*)gp,
        (__attribute__((address_space(3))) void*)l, 16, 0, 0);
}

// ---------------- Kernel 1: fused LN(m) + v = m_n@Wm^T (-> vt) + g = sigmoid(m_n@Wg^T)
// grid (1024, 4): y<2 -> v cols [y*128,+128), y>=2 -> gate cols [(y-2)*128,+128)
// Epilogue via LDS transpose tile -> fully coalesced 16B writes.
__global__ __launch_bounds__(256) void k_vg(
    const float* __restrict__ m, const float* __restrict__ lw,
    const float* __restrict__ lb, const float* __restrict__ Wm,
    const float* __restrict__ Wg, _Float16* __restrict__ vt,
    _Float16* __restrict__ g)
{
    __shared__ __align__(16) _Float16 lds[2 * 128 * 72];   // A | B, reused as T[128][136]
    _Float16* Al = lds;
    _Float16* Bl = lds + 128 * 72;

    int tid  = threadIdx.x;
    int lane = tid & 63;
    int r0 = blockIdx.x * 128;
    bool gate = (blockIdx.y >= 2);
    int c0 = (blockIdx.y & 1) * 128;
    const float* Wp = gate ? Wg : Wm;

    int srow = tid >> 1, skoff = (tid & 1) * 32;
    {
        // LayerNorm: 2 threads per row (32 fp32 elements each), pairwise shuffle combine
        const float4* mg = (const float4*)(m + (size_t)(r0 + srow) * 64 + skoff);
        float xv[32];
        float s1 = 0.f, s2 = 0.f;
        #pragma unroll
        for (int q = 0; q < 8; q++) {
            float4 f = mg[q];
            xv[q*4+0] = f.x; xv[q*4+1] = f.y; xv[q*4+2] = f.z; xv[q*4+3] = f.w;
            s1 += f.x + f.y + f.z + f.w;
            s2 += f.x*f.x + f.y*f.y + f.z*f.z + f.w*f.w;
        }
        s1 += __shfl_xor(s1, 1);
        s2 += __shfl_xor(s2, 1);
        float mu  = s1 * (1.0f / 64.0f);
        float var = s2 * (1.0f / 64.0f) - mu * mu;
        float inv = rsqrtf(var + 1e-5f);

        const float4* wg4 = (const float4*)(Wp + (size_t)(c0 + srow) * 64 + skoff);
        #pragma unroll
        for (int q8 = 0; q8 < 4; q8++) {
            float4 w0 = wg4[q8*2], w1 = wg4[q8*2+1];
            float wf[8] = {w0.x,w0.y,w0.z,w0.w,w1.x,w1.y,w1.z,w1.w};
            f16x8 pa, pb;
            #pragma unroll
            for (int t = 0; t < 8; t++) {
                int c = skoff + q8*8 + t;
                pa[t] = (_Float16)((xv[q8*8+t] - mu) * inv * lw[c] + lb[c]);
                pb[t] = (_Float16)wf[t];
            }
            *(f16x8*)&Al[srow * 72 + skoff + q8*8] = pa;
            *(f16x8*)&Bl[srow * 72 + skoff + q8*8] = pb;
        }
    }
    __syncthreads();

    int wv = tid >> 6;
    int mrow0 = (wv & 1) * 64, ncol0 = (wv >> 1) * 64;
    int quad = lane >> 4, lc = lane & 15;
    // operand swap for gate blocks: af-dim = c, bf-dim = r (so 4-consec acc dim = c for gate, r for v)
    const _Float16* afsrc = gate ? Bl : Al;
    const _Float16* bfsrc = gate ? Al : Bl;

    f32x4 acc[4][4];
    #pragma unroll
    for (int mt = 0; mt < 4; mt++)
        #pragma unroll
        for (int nt = 0; nt < 4; nt++) { f32x4 z4 = {0.f,0.f,0.f,0.f}; acc[mt][nt] = z4; }

    #pragma unroll
    for (int kk = 0; kk < 2; kk++) {
        f16x8 af[4], bf[4];
        int kf = kk * 32 + quad * 8;
        #pragma unroll
        for (int mt = 0; mt < 4; mt++)
            af[mt] = *(const f16x8*)&afsrc[(mrow0 + mt * 16 + lc) * 72 + kf];
        #pragma unroll
        for (int nt = 0; nt < 4; nt++)
            bf[nt] = *(const f16x8*)&bfsrc[(ncol0 + nt * 16 + lc) * 72 + kf];
        #pragma unroll
        for (int mt = 0; mt < 4; mt++)
            #pragma unroll
            for (int nt = 0; nt < 4; nt++)
                acc[mt][nt] = __builtin_amdgcn_mfma_f32_16x16x32_f16(af[mt], bf[nt], acc[mt][nt], 0, 0, 0);
    }

    // stage C into LDS: T[bfdim][afdim], afdim has 4-consecutive per thread -> ds_write_b64
    __syncthreads();
    #pragma unroll
    for (int mt = 0; mt < 4; mt++) {
        int yd = mrow0 + mt * 16 + quad * 4;
        #pragma unroll
        for (int nt = 0; nt < 4; nt++) {
            int xd = ncol0 + nt * 16 + lc;
            h4u pk;
            #pragma unroll
            for (int t = 0; t < 4; t++) {
                float v = acc[mt][nt][t];
                if (gate) v = 1.0f / (1.0f + __expf(-v));
                pk.h[t] = (_Float16)v;
            }
            *(ushort4*)&lds[xd * 136 + yd] = pk.u;
        }
    }
    __syncthreads();

    // coalesced writeout: lanes 0..15 cover one contiguous 256B row
    int s_idx = blockIdx.x >> 2;
    int j0 = (blockIdx.x & 3) * 128;
    #pragma unroll
    for (int p = 0; p < 8; p++) {
        int id = p * 256 + tid;
        int xrow = id >> 4;      // T row (c_local for v, r_local for gate)
        int ch = id & 15;        // 16B chunk (8 f16)
        uint4 val = *(const uint4*)&lds[xrow * 136 + ch * 8];
        if (!gate) {
            int cg = c0 + xrow; int hh = cg >> 5, e = cg & 31;
            *(uint4*)&vt[((size_t)hh * 8192 + s_idx * 32 + e) * 512 + j0 + ch * 8] = val;
        } else {
            *(uint4*)&g[(size_t)(r0 + xrow) * 256 + c0 + ch * 8] = val;
        }
    }
}

// ---------------- Kernel 2: LN(z) -> bias -> softmax -> w (h,i,j) f16
// one block per i; 8 lanes per j-row for coalesced z reads
// softmax tail: one wave per 2 heads, pure in-wave shuffle reduction (no barriers)
__global__ __launch_bounds__(256) void k_bias_softmax(
    const float* __restrict__ z, const float* __restrict__ mask,
    const float* __restrict__ lzw, const float* __restrict__ lzb,
    const float* __restrict__ Wz, _Float16* __restrict__ wout)
{
    __shared__ float WW[8][128];
    __shared__ float LG[8][512];
    __shared__ float Bh[8], Ch[8];
    int tid = threadIdx.x;
    int lane = tid & 63, wv = tid >> 6;

    for (int idx = tid; idx < 1024; idx += 256) {
        int h = idx >> 7, c = idx & 127;
        WW[h][c] = Wz[h * 128 + c] * lzw[c];
    }
    __syncthreads();
    if (tid < 8) {
        float bh = 0.f, ch = 0.f;
        for (int c = 0; c < 128; c++) {
            bh += lzb[c] * Wz[tid * 128 + c];
            ch += WW[tid][c];
        }
        Bh[tid] = bh; Ch[tid] = ch;
    }
    __syncthreads();

    int i = blockIdx.x;
    int sub = tid & 7;        // 8 lanes per row
    int jrow = tid >> 3;      // 32 rows per round
    for (int rr = 0; rr < 16; rr++) {
        int j = rr * 32 + jrow;
        const float4* zp = (const float4*)(z + ((size_t)i * 512 + j) * 128 + sub * 16);
        float s1 = 0.f, s2 = 0.f;
        float a[8] = {0.f,0.f,0.f,0.f,0.f,0.f,0.f,0.f};
        #pragma unroll
        for (int q = 0; q < 4; q++) {
            float4 f = zp[q];
            float xs[4] = {f.x, f.y, f.z, f.w};
            #pragma unroll
            for (int t = 0; t < 4; t++) {
                float x = xs[t];
                s1 += x; s2 += x * x;
                #pragma unroll
                for (int h = 0; h < 8; h++) a[h] += x * WW[h][sub * 16 + q * 4 + t];
            }
        }
        #pragma unroll
        for (int off = 1; off < 8; off <<= 1) {
            s1 += __shfl_xor(s1, off);
            s2 += __shfl_xor(s2, off);
            #pragma unroll
            for (int h = 0; h < 8; h++) a[h] += __shfl_xor(a[h], off);
        }
        if (sub == 0) {
            float mu  = s1 * (1.0f / 128.0f);
            float var = s2 * (1.0f / 128.0f) - mu * mu;
            float inv = rsqrtf(var + 1e-5f);
            float mv  = mask[(size_t)i * 512 + j];
            float madd = (1.0f - mv) * (-1000000.0f);
            #pragma unroll
            for (int h = 0; h < 8; h++)
                LG[h][j] = inv * (a[h] - mu * Ch[h]) + Bh[h] + madd;
        }
    }
    __syncthreads();

    // wave wv handles heads 2*wv and 2*wv+1: in-wave reduce, zero barriers
    #pragma unroll
    for (int hh = 0; hh < 2; hh++) {
        int h = wv * 2 + hh;
        float l[8];
        float mx = -1e30f;
        #pragma unroll
        for (int q = 0; q < 8; q++) {
            l[q] = LG[h][lane + q * 64];
            mx = fmaxf(mx, l[q]);
        }
        mx = wave_max(mx);
        float s = 0.f;
        #pragma unroll
        for (int q = 0; q < 8; q++) {
            l[q] = __expf(l[q] - mx);
            s += l[q];
        }
        s = wave_sum(s);
        float rs = 1.0f / s;
        size_t base = ((size_t)h * 512 + i) * 512;
        #pragma unroll
        for (int q = 0; q < 8; q++)
            wout[base + lane + q * 64] = (_Float16)(l[q] * rs);
    }
}

// ---------------- Kernel 3: o_h = w_h @ vt_h, gate-multiply fused, coalesced RMW of g
// grid (64 c-tiles, 4 i-tiles, 8 heads); operands SWAPPED (af=vt rows n, bf=w rows i)
// m97 structure: global_load_lds width-16 direct staging, linear [128][64] LDS tiles,
// XOR chunk-swizzle (involution) applied to BOTH the global source and the ds_read.
__global__ __launch_bounds__(256) void k_pav(
    const _Float16* __restrict__ wgt, const _Float16* __restrict__ vt,
    _Float16* __restrict__ g)
{
    __shared__ __align__(16) _Float16 lds[128 * 136];  // staging: Al|Bl (2x128x64); epilogue: T[128][136]
    _Float16* Al = lds;
    _Float16* Bl = lds + 128 * 64;
    int h = blockIdx.z;
    int i0 = blockIdx.y * 128;
    int c0 = blockIdx.x * 128;
    const _Float16* A = wgt + (size_t)h * 512 * 512;
    const _Float16* B = vt  + (size_t)h * 8192 * 512;
    int tid = threadIdx.x;
    int lane = tid & 63, wv = tid >> 6;
    int mrow0 = (wv & 1) * 64, ncol0 = (wv >> 1) * 64;
    int quad = lane >> 4, lc = lane & 15;

    // gl_lds addressing: lane covers row (lane>>3) within its 8-row group;
    // pre-swizzled source chunk = (lane&7) ^ (lane>>3)  (row group start is 8-aligned)
    int rsub = lane >> 3;
    int csw  = ((lane & 7) ^ rsub) * 8;   // halves offset within row

    f32x4 acc[4][4];
    #pragma unroll
    for (int mt = 0; mt < 4; mt++)
        #pragma unroll
        for (int nt = 0; nt < 4; nt++) { f32x4 z4 = {0.f,0.f,0.f,0.f}; acc[mt][nt] = z4; }

    for (int kb = 0; kb < 512; kb += 64) {
        // wave wv stages rows [wv*32, wv*32+32) of both operands: 4x 1KB DMA each
        #pragma unroll
        for (int t = 0; t < 4; t++) {
            int r = wv * 32 + t * 8;   // wave-uniform row start
            async16(&Al[r * 64], A + (size_t)(i0 + r + rsub) * 512 + kb + csw);
            async16(&Bl[r * 64], B + (size_t)(c0 + r + rsub) * 512 + kb + csw);
        }
        __syncthreads();   // compiler drains vmcnt(0) before barrier -> tiles visible

        #pragma unroll
        for (int kk = 0; kk < 2; kk++) {
            f16x8 af[4], bf[4];
            #pragma unroll
            for (int mt = 0; mt < 4; mt++) {
                int r = mrow0 + mt * 16 + lc;
                af[mt] = *(const f16x8*)&Bl[r * 64 + (((kk * 4 + quad) ^ (r & 7)) << 3)];  // vt rows (n)
            }
            #pragma unroll
            for (int nt = 0; nt < 4; nt++) {
                int r = ncol0 + nt * 16 + lc;
                bf[nt] = *(const f16x8*)&Al[r * 64 + (((kk * 4 + quad) ^ (r & 7)) << 3)];  // w rows (i)
            }
            #pragma unroll
            for (int mt = 0; mt < 4; mt++)
                #pragma unroll
                for (int nt = 0; nt < 4; nt++)
                    acc[mt][nt] = __builtin_amdgcn_mfma_f32_16x16x32_f16(af[mt], bf[nt], acc[mt][nt], 0, 0, 0);
        }
        __syncthreads();   // all fragment reads done before next overwrite
    }

    // stage C^T into LDS: T[i_local][n_local], 4-consecutive n per thread
    #pragma unroll
    for (int mt = 0; mt < 4; mt++) {
        int yd = mrow0 + mt * 16 + quad * 4;      // n_local
        #pragma unroll
        for (int nt = 0; nt < 4; nt++) {
            int xd = ncol0 + nt * 16 + lc;        // i_local
            h4u pk;
            #pragma unroll
            for (int t = 0; t < 4; t++) pk.h[t] = (_Float16)acc[mt][nt][t];
            *(ushort4*)&lds[xd * 136 + yd] = pk.u;
        }
    }
    __syncthreads();

    // coalesced gate-RMW writeout: og = g * o (in place over g)
    #pragma unroll
    for (int p = 0; p < 8; p++) {
        int id = p * 256 + tid;
        int il = id >> 4;          // i_local
        int ch = id & 15;          // 8 n per chunk
        int ng = c0 + ch * 8;
        int sj = ng >> 5, e = ng & 31;
        size_t base = ((size_t)sj * 512 + i0 + il) * HC + h * 32 + e;
        h8u ov, gv, res;
        ov.u = *(const uint4*)&lds[il * 136 + ch * 8];
        gv.u = *(const uint4*)&g[base];
        #pragma unroll
        for (int t = 0; t < 8; t++) res.h[t] = (_Float16)((float)ov.h[t] * (float)gv.h[t]);
        *(uint4*)&g[base] = res.u;
    }
}

// ---------------- Kernel 4: out = og @ Wo^T  (131072x256 @ 256x64), fp32 out
// operands swapped (af=Wo rows c, bf=og rows r) -> b128 LDS epilogue, coalesced stores
__global__ __launch_bounds__(256) void k_out(
    const _Float16* __restrict__ og, const float* __restrict__ Wo,
    float* __restrict__ out)
{
    __shared__ __align__(16) char smem[34816];
    _Float16* Blds = (_Float16*)smem;      // 64 x 264
    float* Tf = (float*)smem;              // 128 x 68
    int tid = threadIdx.x;
    int lane = tid & 63, wv = tid >> 6;
    int r0 = blockIdx.x * 128;

    {
        const float4* src = (const float4*)(Wo + (size_t)(tid >> 2) * 256 + (tid & 3) * 64);
        #pragma unroll
        for (int q8 = 0; q8 < 8; q8++) {
            float4 w0 = src[q8*2], w1 = src[q8*2+1];
            float wf[8] = {w0.x,w0.y,w0.z,w0.w,w1.x,w1.y,w1.z,w1.w};
            f16x8 p;
            #pragma unroll
            for (int t = 0; t < 8; t++) p[t] = (_Float16)wf[t];
            *(f16x8*)&Blds[(tid >> 2) * 264 + (tid & 3) * 64 + q8 * 8] = p;
        }
    }
    __syncthreads();

    int quad = lane >> 4, lc = lane & 15;
    f32x4 acc[4][2];   // [c-tiles][r-tiles]
    #pragma unroll
    for (int ct = 0; ct < 4; ct++)
        #pragma unroll
        for (int rt = 0; rt < 2; rt++) { f32x4 z4 = {0.f,0.f,0.f,0.f}; acc[ct][rt] = z4; }

    for (int kb = 0; kb < 256; kb += 32) {
        int kf = kb + quad * 8;
        f16x8 bf[2];
        #pragma unroll
        for (int rt = 0; rt < 2; rt++) {
            int row = r0 + wv * 32 + rt * 16 + lc;
            bf[rt] = *(const f16x8*)(og + (size_t)row * HC + kf);
        }
        f16x8 af[4];
        #pragma unroll
        for (int ct = 0; ct < 4; ct++)
            af[ct] = *(const f16x8*)&Blds[(ct * 16 + lc) * 264 + kf];
        #pragma unroll
        for (int ct = 0; ct < 4; ct++)
            #pragma unroll
            for (int rt = 0; rt < 2; rt++)
                acc[ct][rt] = __builtin_amdgcn_mfma_f32_16x16x32_f16(af[ct], bf[rt], acc[ct][rt], 0, 0, 0);
    }

    __syncthreads();
    // T[r_local][c], 4-consecutive c per thread -> b128 LDS write
    #pragma unroll
    for (int ct = 0; ct < 4; ct++) {
        int cd = ct * 16 + quad * 4;
        #pragma unroll
        for (int rt = 0; rt < 2; rt++) {
            int rd = wv * 32 + rt * 16 + lc;
            *(f32x4*)&Tf[rd * 68 + cd] = acc[ct][rt];
        }
    }
    __syncthreads();

    #pragma unroll
    for (int p = 0; p < 8; p++) {
        int id = p * 256 + tid;
        int rl = id >> 4;          // r_local
        int ch = id & 15;          // 4 f32 per chunk
        uint4 v = *(const uint4*)&Tf[rl * 68 + ch * 4];
        *(uint4*)&out[(size_t)(r0 + rl) * 64 + ch * 4] = v;
    }
}

extern "C" void kernel_launch(void* const* d_in, const int* in_sizes, int n_in,
                              void* d_out, int out_size, void* d_ws, size_t ws_size,
                              hipStream_t stream) {
    const float* m    = (const float*)d_in[0];
    const float* z    = (const float*)d_in[1];
    const float* mask = (const float*)d_in[2];
    const float* lnmw = (const float*)d_in[3];
    const float* lnmb = (const float*)d_in[4];
    const float* lnzw = (const float*)d_in[5];
    const float* lnzb = (const float*)d_in[6];
    const float* Wm   = (const float*)d_in[7];
    const float* Wg   = (const float*)d_in[8];
    const float* Wz   = (const float*)d_in[9];
    const float* Wo   = (const float*)d_in[10];
    float* out = (float*)d_out;

    char* ws = (char*)d_ws;
    _Float16* vt = (_Float16*)ws;                 // 64 MiB  [k_vg -> k_pav]
    _Float16* g  = (_Float16*)(ws + 67108864);    // 64 MiB  [k_vg -> k_pav(in-place og) -> k_out]
    _Float16* w  = (_Float16*)d_out;              // 4 MiB, parked in d_out (33.5 MB), dead before k_out writes
    (void)in_sizes; (void)n_in; (void)out_size; (void)ws_size;

    k_vg<<<dim3(1024, 4), 256, 0, stream>>>(m, lnmw, lnmb, Wm, Wg, vt, g);
    k_bias_softmax<<<512, 256, 0, stream>>>(z, mask, lnzw, lnzb, Wz, w);
    k_pav<<<dim3(64, 4, 8), 256, 0, stream>>>(w, vt, g);
    k_out<<<1024, 256, 0, stream>>>(g, Wo, out);
}

// Round 3
// 389.887 us; speedup vs baseline: 1.0345x; 1.0251x over previous
//
#include <hip/hip_runtime.h>

#define HC 256   // H*C_H

typedef _Float16 f16x8 __attribute__((ext_vector_type(8)));
typedef float f32x4 __attribute__((ext_vector_type(4)));

union h4u { ushort4 u; _Float16 h[4]; };
union h8u { uint4 u; f16x8 h; };

__device__ __forceinline__ float wave_sum(float v) {
    #pragma unroll
    for (int off = 32; off; off >>= 1) v += __shfl_xor(v, off);
    return v;
}
__device__ __forceinline__ float wave_max(float v) {
    #pragma unroll
    for (int off = 32; off; off >>= 1) v = fmaxf(v, __shfl_xor(v, off));
    return v;
}

// async global->LDS DMA, 16B per lane (global_load_lds_dwordx4)
__device__ __forceinline__ void async16(_Float16* l, const _Float16* gp) {
    __builtin_amdgcn_global_load_lds(
        (const __attribute__((address_space(1))) void*)gp,
        (__attribute__((address_space(3))) void*)l, 16, 0, 0);
}

// ---------------- Kernel 1: fused LN(m) + v = m_n@Wm^T (-> vt) + g = sigmoid(m_n@Wg^T)
// grid (1024, 4): y<2 -> v cols [y*128,+128), y>=2 -> gate cols [(y-2)*128,+128)
// Epilogue via LDS transpose tile -> fully coalesced 16B writes.
__global__ __launch_bounds__(256) void k_vg(
    const float* __restrict__ m, const float* __restrict__ lw,
    const float* __restrict__ lb, const float* __restrict__ Wm,
    const float* __restrict__ Wg, _Float16* __restrict__ vt,
    _Float16* __restrict__ g)
{
    __shared__ __align__(16) _Float16 lds[2 * 128 * 72];   // A | B, reused as T[128][136]
    _Float16* Al = lds;
    _Float16* Bl = lds + 128 * 72;

    int tid  = threadIdx.x;
    int lane = tid & 63;
    int r0 = blockIdx.x * 128;
    bool gate = (blockIdx.y >= 2);
    int c0 = (blockIdx.y & 1) * 128;
    const float* Wp = gate ? Wg : Wm;

    int srow = tid >> 1, skoff = (tid & 1) * 32;
    {
        // LayerNorm: 2 threads per row (32 fp32 elements each), pairwise shuffle combine
        const float4* mg = (const float4*)(m + (size_t)(r0 + srow) * 64 + skoff);
        float xv[32];
        float s1 = 0.f, s2 = 0.f;
        #pragma unroll
        for (int q = 0; q < 8; q++) {
            float4 f = mg[q];
            xv[q*4+0] = f.x; xv[q*4+1] = f.y; xv[q*4+2] = f.z; xv[q*4+3] = f.w;
            s1 += f.x + f.y + f.z + f.w;
            s2 += f.x*f.x + f.y*f.y + f.z*f.z + f.w*f.w;
        }
        s1 += __shfl_xor(s1, 1);
        s2 += __shfl_xor(s2, 1);
        float mu  = s1 * (1.0f / 64.0f);
        float var = s2 * (1.0f / 64.0f) - mu * mu;
        float inv = rsqrtf(var + 1e-5f);

        const float4* wg4 = (const float4*)(Wp + (size_t)(c0 + srow) * 64 + skoff);
        #pragma unroll
        for (int q8 = 0; q8 < 4; q8++) {
            float4 w0 = wg4[q8*2], w1 = wg4[q8*2+1];
            float wf[8] = {w0.x,w0.y,w0.z,w0.w,w1.x,w1.y,w1.z,w1.w};
            f16x8 pa, pb;
            #pragma unroll
            for (int t = 0; t < 8; t++) {
                int c = skoff + q8*8 + t;
                pa[t] = (_Float16)((xv[q8*8+t] - mu) * inv * lw[c] + lb[c]);
                pb[t] = (_Float16)wf[t];
            }
            *(f16x8*)&Al[srow * 72 + skoff + q8*8] = pa;
            *(f16x8*)&Bl[srow * 72 + skoff + q8*8] = pb;
        }
    }
    __syncthreads();

    int wv = tid >> 6;
    int mrow0 = (wv & 1) * 64, ncol0 = (wv >> 1) * 64;
    int quad = lane >> 4, lc = lane & 15;
    // operand swap for gate blocks: af-dim = c, bf-dim = r (so 4-consec acc dim = c for gate, r for v)
    const _Float16* afsrc = gate ? Bl : Al;
    const _Float16* bfsrc = gate ? Al : Bl;

    f32x4 acc[4][4];
    #pragma unroll
    for (int mt = 0; mt < 4; mt++)
        #pragma unroll
        for (int nt = 0; nt < 4; nt++) { f32x4 z4 = {0.f,0.f,0.f,0.f}; acc[mt][nt] = z4; }

    #pragma unroll
    for (int kk = 0; kk < 2; kk++) {
        f16x8 af[4], bf[4];
        int kf = kk * 32 + quad * 8;
        #pragma unroll
        for (int mt = 0; mt < 4; mt++)
            af[mt] = *(const f16x8*)&afsrc[(mrow0 + mt * 16 + lc) * 72 + kf];
        #pragma unroll
        for (int nt = 0; nt < 4; nt++)
            bf[nt] = *(const f16x8*)&bfsrc[(ncol0 + nt * 16 + lc) * 72 + kf];
        #pragma unroll
        for (int mt = 0; mt < 4; mt++)
            #pragma unroll
            for (int nt = 0; nt < 4; nt++)
                acc[mt][nt] = __builtin_amdgcn_mfma_f32_16x16x32_f16(af[mt], bf[nt], acc[mt][nt], 0, 0, 0);
    }

    // stage C into LDS: T[bfdim][afdim], afdim has 4-consecutive per thread -> ds_write_b64
    __syncthreads();
    #pragma unroll
    for (int mt = 0; mt < 4; mt++) {
        int yd = mrow0 + mt * 16 + quad * 4;
        #pragma unroll
        for (int nt = 0; nt < 4; nt++) {
            int xd = ncol0 + nt * 16 + lc;
            h4u pk;
            #pragma unroll
            for (int t = 0; t < 4; t++) {
                float v = acc[mt][nt][t];
                if (gate) v = 1.0f / (1.0f + __expf(-v));
                pk.h[t] = (_Float16)v;
            }
            *(ushort4*)&lds[xd * 136 + yd] = pk.u;
        }
    }
    __syncthreads();

    // coalesced writeout: lanes 0..15 cover one contiguous 256B row
    int s_idx = blockIdx.x >> 2;
    int j0 = (blockIdx.x & 3) * 128;
    #pragma unroll
    for (int p = 0; p < 8; p++) {
        int id = p * 256 + tid;
        int xrow = id >> 4;      // T row (c_local for v, r_local for gate)
        int ch = id & 15;        // 16B chunk (8 f16)
        uint4 val = *(const uint4*)&lds[xrow * 136 + ch * 8];
        if (!gate) {
            int cg = c0 + xrow; int hh = cg >> 5, e = cg & 31;
            *(uint4*)&vt[((size_t)hh * 8192 + s_idx * 32 + e) * 512 + j0 + ch * 8] = val;
        } else {
            *(uint4*)&g[(size_t)(r0 + xrow) * 256 + c0 + ch * 8] = val;
        }
    }
}

// ---------------- Kernel 2: LN(z) -> bias -> softmax -> w (h,i,j) f16
// one block per i; 8 lanes per j-row for coalesced z reads
// softmax tail: one wave per 2 heads, pure in-wave shuffle reduction (no barriers)
__global__ __launch_bounds__(256) void k_bias_softmax(
    const float* __restrict__ z, const float* __restrict__ mask,
    const float* __restrict__ lzw, const float* __restrict__ lzb,
    const float* __restrict__ Wz, _Float16* __restrict__ wout)
{
    __shared__ float WW[8][128];
    __shared__ float LG[8][512];
    __shared__ float Bh[8], Ch[8];
    int tid = threadIdx.x;
    int lane = tid & 63, wv = tid >> 6;

    for (int idx = tid; idx < 1024; idx += 256) {
        int h = idx >> 7, c = idx & 127;
        WW[h][c] = Wz[h * 128 + c] * lzw[c];
    }
    __syncthreads();
    if (tid < 8) {
        float bh = 0.f, ch = 0.f;
        for (int c = 0; c < 128; c++) {
            bh += lzb[c] * Wz[tid * 128 + c];
            ch += WW[tid][c];
        }
        Bh[tid] = bh; Ch[tid] = ch;
    }
    __syncthreads();

    int i = blockIdx.x;
    int sub = tid & 7;        // 8 lanes per row
    int jrow = tid >> 3;      // 32 rows per round
    for (int rr = 0; rr < 16; rr++) {
        int j = rr * 32 + jrow;
        const float4* zp = (const float4*)(z + ((size_t)i * 512 + j) * 128 + sub * 16);
        float s1 = 0.f, s2 = 0.f;
        float a[8] = {0.f,0.f,0.f,0.f,0.f,0.f,0.f,0.f};
        #pragma unroll
        for (int q = 0; q < 4; q++) {
            float4 f = zp[q];
            float xs[4] = {f.x, f.y, f.z, f.w};
            #pragma unroll
            for (int t = 0; t < 4; t++) {
                float x = xs[t];
                s1 += x; s2 += x * x;
                #pragma unroll
                for (int h = 0; h < 8; h++) a[h] += x * WW[h][sub * 16 + q * 4 + t];
            }
        }
        #pragma unroll
        for (int off = 1; off < 8; off <<= 1) {
            s1 += __shfl_xor(s1, off);
            s2 += __shfl_xor(s2, off);
            #pragma unroll
            for (int h = 0; h < 8; h++) a[h] += __shfl_xor(a[h], off);
        }
        if (sub == 0) {
            float mu  = s1 * (1.0f / 128.0f);
            float var = s2 * (1.0f / 128.0f) - mu * mu;
            float inv = rsqrtf(var + 1e-5f);
            float mv  = mask[(size_t)i * 512 + j];
            float madd = (1.0f - mv) * (-1000000.0f);
            #pragma unroll
            for (int h = 0; h < 8; h++)
                LG[h][j] = inv * (a[h] - mu * Ch[h]) + Bh[h] + madd;
        }
    }
    __syncthreads();

    // wave wv handles heads 2*wv and 2*wv+1: in-wave reduce, zero barriers
    #pragma unroll
    for (int hh = 0; hh < 2; hh++) {
        int h = wv * 2 + hh;
        float l[8];
        float mx = -1e30f;
        #pragma unroll
        for (int q = 0; q < 8; q++) {
            l[q] = LG[h][lane + q * 64];
            mx = fmaxf(mx, l[q]);
        }
        mx = wave_max(mx);
        float s = 0.f;
        #pragma unroll
        for (int q = 0; q < 8; q++) {
            l[q] = __expf(l[q] - mx);
            s += l[q];
        }
        s = wave_sum(s);
        float rs = 1.0f / s;
        size_t base = ((size_t)h * 512 + i) * 512;
        #pragma unroll
        for (int q = 0; q < 8; q++)
            wout[base + lane + q * 64] = (_Float16)(l[q] * rs);
    }
}

// ---------------- Kernel 3: o_h = w_h @ vt_h, gate-multiply fused, coalesced RMW of g
// grid (64 c-tiles, 4 i-tiles, 8 heads); operands SWAPPED (af=vt rows n, bf=w rows i)
// 2-phase double-buffered pipeline: STAGE(t+1) hoisted above compute(t),
// single __syncthreads per K-step (its vmcnt(0)+lgkmcnt(0) drain lands AFTER
// the compute phase -> DMA latency absorbed by ds_read+MFMA instead of exposed).
__global__ __launch_bounds__(256) void k_pav(
    const _Float16* __restrict__ wgt, const _Float16* __restrict__ vt,
    _Float16* __restrict__ g)
{
    __shared__ __align__(16) _Float16 lds[2 * 2 * 128 * 64];  // [buf][{A,B}][128][64] = 64 KiB
    int h = blockIdx.z;
    int i0 = blockIdx.y * 128;
    int c0 = blockIdx.x * 128;
    const _Float16* A = wgt + (size_t)h * 512 * 512;
    const _Float16* B = vt  + (size_t)h * 8192 * 512;
    int tid = threadIdx.x;
    int lane = tid & 63, wv = tid >> 6;
    int mrow0 = (wv & 1) * 64, ncol0 = (wv >> 1) * 64;
    int quad = lane >> 4, lc = lane & 15;

    // gl_lds addressing: lane covers row (lane>>3) within its 8-row group;
    // pre-swizzled source chunk = (lane&7) ^ (lane>>3)  (row group start is 8-aligned)
    int rsub = lane >> 3;
    int csw  = ((lane & 7) ^ rsub) * 8;   // halves offset within row

    const _Float16* Ag = A + (size_t)(i0 + wv * 32 + rsub) * 512 + csw;
    const _Float16* Bg = B + (size_t)(c0 + wv * 32 + rsub) * 512 + csw;

    f32x4 acc[4][4];
    #pragma unroll
    for (int mt = 0; mt < 4; mt++)
        #pragma unroll
        for (int nt = 0; nt < 4; nt++) { f32x4 z4 = {0.f,0.f,0.f,0.f}; acc[mt][nt] = z4; }

    // wave wv stages rows [wv*32, wv*32+32) of both operands: 4x 1KB DMA each
    auto stage = [&](int buf, int kb) {
        _Float16* Als = lds + buf * (2 * 128 * 64);
        _Float16* Bls = Als + 128 * 64;
        #pragma unroll
        for (int t = 0; t < 4; t++) {
            int r = wv * 32 + t * 8;   // wave-uniform LDS row start
            async16(&Als[r * 64], Ag + (size_t)(t * 8) * 512 + kb);
            async16(&Bls[r * 64], Bg + (size_t)(t * 8) * 512 + kb);
        }
    };

    stage(0, 0);
    __syncthreads();   // drain prologue DMAs (one exposed latency, once)

    int cur = 0;
    for (int kb = 0; kb < 512; kb += 64) {
        if (kb + 64 < 512) stage(cur ^ 1, kb + 64);   // prefetch next tile

        const _Float16* Al = lds + cur * (2 * 128 * 64);
        const _Float16* Bl = Al + 128 * 64;
        #pragma unroll
        for (int kk = 0; kk < 2; kk++) {
            f16x8 af[4], bf[4];
            #pragma unroll
            for (int mt = 0; mt < 4; mt++) {
                int r = mrow0 + mt * 16 + lc;
                af[mt] = *(const f16x8*)&Bl[r * 64 + (((kk * 4 + quad) ^ (r & 7)) << 3)];  // vt rows (n)
            }
            #pragma unroll
            for (int nt = 0; nt < 4; nt++) {
                int r = ncol0 + nt * 16 + lc;
                bf[nt] = *(const f16x8*)&Al[r * 64 + (((kk * 4 + quad) ^ (r & 7)) << 3)];  // w rows (i)
            }
            #pragma unroll
            for (int mt = 0; mt < 4; mt++)
                #pragma unroll
                for (int nt = 0; nt < 4; nt++)
                    acc[mt][nt] = __builtin_amdgcn_mfma_f32_16x16x32_f16(af[mt], bf[nt], acc[mt][nt], 0, 0, 0);
        }

        // single barrier per K-step: drains prefetch DMAs (after full compute
        // overlap) AND guarantees this tile's ds_reads retired before the
        // buffer is overwritten next iteration.
        __syncthreads();
        cur ^= 1;
    }

    // stage C^T into LDS: T[i_local][n_local] reusing buffer 0 (loop's final
    // __syncthreads guarantees all fragment reads retired block-wide)
    #pragma unroll
    for (int mt = 0; mt < 4; mt++) {
        int yd = mrow0 + mt * 16 + quad * 4;      // n_local
        #pragma unroll
        for (int nt = 0; nt < 4; nt++) {
            int xd = ncol0 + nt * 16 + lc;        // i_local
            h4u pk;
            #pragma unroll
            for (int t = 0; t < 4; t++) pk.h[t] = (_Float16)acc[mt][nt][t];
            *(ushort4*)&lds[xd * 136 + yd] = pk.u;
        }
    }
    __syncthreads();

    // coalesced gate-RMW writeout: og = g * o (in place over g)
    #pragma unroll
    for (int p = 0; p < 8; p++) {
        int id = p * 256 + tid;
        int il = id >> 4;          // i_local
        int ch = id & 15;          // 8 n per chunk
        int ng = c0 + ch * 8;
        int sj = ng >> 5, e = ng & 31;
        size_t base = ((size_t)sj * 512 + i0 + il) * HC + h * 32 + e;
        h8u ov, gv, res;
        ov.u = *(const uint4*)&lds[il * 136 + ch * 8];
        gv.u = *(const uint4*)&g[base];
        #pragma unroll
        for (int t = 0; t < 8; t++) res.h[t] = (_Float16)((float)ov.h[t] * (float)gv.h[t]);
        *(uint4*)&g[base] = res.u;
    }
}

// ---------------- Kernel 4: out = og @ Wo^T  (131072x256 @ 256x64), fp32 out
// operands swapped (af=Wo rows c, bf=og rows r) -> b128 LDS epilogue, coalesced stores
__global__ __launch_bounds__(256) void k_out(
    const _Float16* __restrict__ og, const float* __restrict__ Wo,
    float* __restrict__ out)
{
    __shared__ __align__(16) char smem[34816];
    _Float16* Blds = (_Float16*)smem;      // 64 x 264
    float* Tf = (float*)smem;              // 128 x 68
    int tid = threadIdx.x;
    int lane = tid & 63, wv = tid >> 6;
    int r0 = blockIdx.x * 128;

    {
        const float4* src = (const float4*)(Wo + (size_t)(tid >> 2) * 256 + (tid & 3) * 64);
        #pragma unroll
        for (int q8 = 0; q8 < 8; q8++) {
            float4 w0 = src[q8*2], w1 = src[q8*2+1];
            float wf[8] = {w0.x,w0.y,w0.z,w0.w,w1.x,w1.y,w1.z,w1.w};
            f16x8 p;
            #pragma unroll
            for (int t = 0; t < 8; t++) p[t] = (_Float16)wf[t];
            *(f16x8*)&Blds[(tid >> 2) * 264 + (tid & 3) * 64 + q8 * 8] = p;
        }
    }
    __syncthreads();

    int quad = lane >> 4, lc = lane & 15;
    f32x4 acc[4][2];   // [c-tiles][r-tiles]
    #pragma unroll
    for (int ct = 0; ct < 4; ct++)
        #pragma unroll
        for (int rt = 0; rt < 2; rt++) { f32x4 z4 = {0.f,0.f,0.f,0.f}; acc[ct][rt] = z4; }

    for (int kb = 0; kb < 256; kb += 32) {
        int kf = kb + quad * 8;
        f16x8 bf[2];
        #pragma unroll
        for (int rt = 0; rt < 2; rt++) {
            int row = r0 + wv * 32 + rt * 16 + lc;
            bf[rt] = *(const f16x8*)(og + (size_t)row * HC + kf);
        }
        f16x8 af[4];
        #pragma unroll
        for (int ct = 0; ct < 4; ct++)
            af[ct] = *(const f16x8*)&Blds[(ct * 16 + lc) * 264 + kf];
        #pragma unroll
        for (int ct = 0; ct < 4; ct++)
            #pragma unroll
            for (int rt = 0; rt < 2; rt++)
                acc[ct][rt] = __builtin_amdgcn_mfma_f32_16x16x32_f16(af[ct], bf[rt], acc[ct][rt], 0, 0, 0);
    }

    __syncthreads();
    // T[r_local][c], 4-consecutive c per thread -> b128 LDS write
    #pragma unroll
    for (int ct = 0; ct < 4; ct++) {
        int cd = ct * 16 + quad * 4;
        #pragma unroll
        for (int rt = 0; rt < 2; rt++) {
            int rd = wv * 32 + rt * 16 + lc;
            *(f32x4*)&Tf[rd * 68 + cd] = acc[ct][rt];
        }
    }
    __syncthreads();

    #pragma unroll
    for (int p = 0; p < 8; p++) {
        int id = p * 256 + tid;
        int rl = id >> 4;          // r_local
        int ch = id & 15;          // 4 f32 per chunk
        uint4 v = *(const uint4*)&Tf[rl * 68 + ch * 4];
        *(uint4*)&out[(size_t)(r0 + rl) * 64 + ch * 4] = v;
    }
}

extern "C" void kernel_launch(void* const* d_in, const int* in_sizes, int n_in,
                              void* d_out, int out_size, void* d_ws, size_t ws_size,
                              hipStream_t stream) {
    const float* m    = (const float*)d_in[0];
    const float* z    = (const float*)d_in[1];
    const float* mask = (const float*)d_in[2];
    const float* lnmw = (const float*)d_in[3];
    const float* lnmb = (const float*)d_in[4];
    const float* lnzw = (const float*)d_in[5];
    const float* lnzb = (const float*)d_in[6];
    const float* Wm   = (const float*)d_in[7];
    const float* Wg   = (const float*)d_in[8];
    const float* Wz   = (const float*)d_in[9];
    const float* Wo   = (const float*)d_in[10];
    float* out = (float*)d_out;

    char* ws = (char*)d_ws;
    _Float16* vt = (_Float16*)ws;                 // 64 MiB  [k_vg -> k_pav]
    _Float16* g  = (_Float16*)(ws + 67108864);    // 64 MiB  [k_vg -> k_pav(in-place og) -> k_out]
    _Float16* w  = (_Float16*)d_out;              // 4 MiB, parked in d_out (33.5 MB), dead before k_out writes
    (void)in_sizes; (void)n_in; (void)out_size; (void)ws_size;

    k_vg<<<dim3(1024, 4), 256, 0, stream>>>(m, lnmw, lnmb, Wm, Wg, vt, g);
    k_bias_softmax<<<512, 256, 0, stream>>>(z, mask, lnzw, lnzb, Wz, w);
    k_pav<<<dim3(64, 4, 8), 256, 0, stream>>>(w, vt, g);
    k_out<<<1024, 256, 0, stream>>>(g, Wo, out);
}

// Round 4
// 377.175 us; speedup vs baseline: 1.0694x; 1.0337x over previous
//
#include <hip/hip_runtime.h>

#define HC 256   // H*C_H

typedef _Float16 f16x8 __attribute__((ext_vector_type(8)));
typedef float f32x4 __attribute__((ext_vector_type(4)));

union h4u { ushort4 u; _Float16 h[4]; };
union h8u { uint4 u; f16x8 h; };

__device__ __forceinline__ float wave_sum(float v) {
    #pragma unroll
    for (int off = 32; off; off >>= 1) v += __shfl_xor(v, off);
    return v;
}
__device__ __forceinline__ float wave_max(float v) {
    #pragma unroll
    for (int off = 32; off; off >>= 1) v = fmaxf(v, __shfl_xor(v, off));
    return v;
}

// async global->LDS DMA, 16B per lane (global_load_lds_dwordx4)
__device__ __forceinline__ void async16(_Float16* l, const _Float16* gp) {
    __builtin_amdgcn_global_load_lds(
        (const __attribute__((address_space(1))) void*)gp,
        (__attribute__((address_space(3))) void*)l, 16, 0, 0);
}

// ---------------- Kernel 0: one-shot weight f16 conversion: Wf16[0:256]=Wm, [256:512]=Wg
__global__ __launch_bounds__(256) void k_wcvt(
    const float* __restrict__ Wm, const float* __restrict__ Wg,
    _Float16* __restrict__ Wf)
{
    int i = (blockIdx.x * 256 + threadIdx.x) * 4;   // 32 blocks -> 32768 elems
    const float* src = (i < 16384) ? (Wm + i) : (Wg + (i - 16384));
    float4 f = *(const float4*)src;
    h4u p;
    p.h[0] = (_Float16)f.x; p.h[1] = (_Float16)f.y;
    p.h[2] = (_Float16)f.z; p.h[3] = (_Float16)f.w;
    *(ushort4*)&Wf[i] = p.u;
}

// ---------------- Kernel 1: fused LN(m) + v = m_n@Wm^T (-> vt) + g = sigmoid(m_n@Wg^T)
// grid 1024: ONE block per 128-row tile computes all 4 col-tiles (v x2, gate x2).
// LN + A-staging done ONCE; B fragments loaded from L2-resident f16 weight table.
__global__ __launch_bounds__(256) void k_vg(
    const float* __restrict__ m, const float* __restrict__ lw,
    const float* __restrict__ lb, const _Float16* __restrict__ Wf,
    _Float16* __restrict__ vt, _Float16* __restrict__ g)
{
    __shared__ __align__(16) _Float16 Al[128 * 72];    // m_n tile (persistent)
    __shared__ __align__(16) _Float16 T[128 * 136];    // epilogue transpose tile
    int tid  = threadIdx.x;
    int lane = tid & 63;
    int r0 = blockIdx.x * 128;

    int srow = tid >> 1, skoff = (tid & 1) * 32;
    {
        // LayerNorm: 2 threads per row (32 fp32 elements each), pairwise shuffle combine
        const float4* mg = (const float4*)(m + (size_t)(r0 + srow) * 64 + skoff);
        float xv[32];
        float s1 = 0.f, s2 = 0.f;
        #pragma unroll
        for (int q = 0; q < 8; q++) {
            float4 f = mg[q];
            xv[q*4+0] = f.x; xv[q*4+1] = f.y; xv[q*4+2] = f.z; xv[q*4+3] = f.w;
            s1 += f.x + f.y + f.z + f.w;
            s2 += f.x*f.x + f.y*f.y + f.z*f.z + f.w*f.w;
        }
        s1 += __shfl_xor(s1, 1);
        s2 += __shfl_xor(s2, 1);
        float mu  = s1 * (1.0f / 64.0f);
        float var = s2 * (1.0f / 64.0f) - mu * mu;
        float inv = rsqrtf(var + 1e-5f);

        #pragma unroll
        for (int q8 = 0; q8 < 4; q8++) {
            f16x8 pa;
            #pragma unroll
            for (int t = 0; t < 8; t++) {
                int c = skoff + q8*8 + t;
                pa[t] = (_Float16)((xv[q8*8+t] - mu) * inv * lw[c] + lb[c]);
            }
            *(f16x8*)&Al[srow * 72 + skoff + q8*8] = pa;
        }
    }
    __syncthreads();

    int wv = tid >> 6;
    int mrow0 = (wv & 1) * 64, ncol0 = (wv >> 1) * 64;
    int quad = lane >> 4, lc = lane & 15;
    int s_idx = blockIdx.x >> 2;
    int j0 = (blockIdx.x & 3) * 128;

    #pragma unroll 1
    for (int ct = 0; ct < 4; ct++) {
        bool gate = (ct >= 2);
        int c0 = (ct & 1) * 128;
        int wbase = ct * 128;          // row base into Wf16 table

        f32x4 acc[4][4];
        #pragma unroll
        for (int mt = 0; mt < 4; mt++)
            #pragma unroll
            for (int nt = 0; nt < 4; nt++) { f32x4 z4 = {0.f,0.f,0.f,0.f}; acc[mt][nt] = z4; }

        #pragma unroll
        for (int kk = 0; kk < 2; kk++) {
            f16x8 af[4], bf[4];
            int kf = kk * 32 + quad * 8;
            if (!gate) {
                // af = m_n rows (r), bf = weight rows (c)
                #pragma unroll
                for (int mt = 0; mt < 4; mt++)
                    af[mt] = *(const f16x8*)&Al[(mrow0 + mt * 16 + lc) * 72 + kf];
                #pragma unroll
                for (int nt = 0; nt < 4; nt++)
                    bf[nt] = *(const f16x8*)&Wf[(size_t)(wbase + ncol0 + nt * 16 + lc) * 64 + kf];
            } else {
                // swapped: af = weight rows (c), bf = m_n rows (r)
                #pragma unroll
                for (int mt = 0; mt < 4; mt++)
                    af[mt] = *(const f16x8*)&Wf[(size_t)(wbase + mrow0 + mt * 16 + lc) * 64 + kf];
                #pragma unroll
                for (int nt = 0; nt < 4; nt++)
                    bf[nt] = *(const f16x8*)&Al[(ncol0 + nt * 16 + lc) * 72 + kf];
            }
            #pragma unroll
            for (int mt = 0; mt < 4; mt++)
                #pragma unroll
                for (int nt = 0; nt < 4; nt++)
                    acc[mt][nt] = __builtin_amdgcn_mfma_f32_16x16x32_f16(af[mt], bf[nt], acc[mt][nt], 0, 0, 0);
        }

        // stage C into LDS: T[bfdim][afdim], afdim has 4-consecutive per thread
        #pragma unroll
        for (int mt = 0; mt < 4; mt++) {
            int yd = mrow0 + mt * 16 + quad * 4;
            #pragma unroll
            for (int nt = 0; nt < 4; nt++) {
                int xd = ncol0 + nt * 16 + lc;
                h4u pk;
                #pragma unroll
                for (int t = 0; t < 4; t++) {
                    float v = acc[mt][nt][t];
                    if (gate) v = 1.0f / (1.0f + __expf(-v));
                    pk.h[t] = (_Float16)v;
                }
                *(ushort4*)&T[xd * 136 + yd] = pk.u;
            }
        }
        __syncthreads();

        // coalesced writeout: lanes 0..15 cover one contiguous 256B row
        #pragma unroll
        for (int p = 0; p < 8; p++) {
            int id = p * 256 + tid;
            int xrow = id >> 4;      // T row (c_local for v, r_local for gate)
            int ch = id & 15;        // 16B chunk (8 f16)
            uint4 val = *(const uint4*)&T[xrow * 136 + ch * 8];
            if (!gate) {
                int cg = c0 + xrow; int hh = cg >> 5, e = cg & 31;
                *(uint4*)&vt[((size_t)hh * 8192 + s_idx * 32 + e) * 512 + j0 + ch * 8] = val;
            } else {
                *(uint4*)&g[(size_t)(r0 + xrow) * 256 + c0 + ch * 8] = val;
            }
        }
        __syncthreads();   // T consumed before next ct overwrites it
    }
}

// ---------------- Kernel 2: LN(z) -> bias -> softmax -> w (h,i,j) f16
// one block per i; 8 lanes per j-row for coalesced z reads
// softmax tail: one wave per 2 heads, pure in-wave shuffle reduction (no barriers)
__global__ __launch_bounds__(256) void k_bias_softmax(
    const float* __restrict__ z, const float* __restrict__ mask,
    const float* __restrict__ lzw, const float* __restrict__ lzb,
    const float* __restrict__ Wz, _Float16* __restrict__ wout)
{
    __shared__ float WW[8][128];
    __shared__ float LG[8][512];
    __shared__ float Bh[8], Ch[8];
    int tid = threadIdx.x;
    int lane = tid & 63, wv = tid >> 6;

    for (int idx = tid; idx < 1024; idx += 256) {
        int h = idx >> 7, c = idx & 127;
        WW[h][c] = Wz[h * 128 + c] * lzw[c];
    }
    __syncthreads();
    if (tid < 8) {
        float bh = 0.f, ch = 0.f;
        for (int c = 0; c < 128; c++) {
            bh += lzb[c] * Wz[tid * 128 + c];
            ch += WW[tid][c];
        }
        Bh[tid] = bh; Ch[tid] = ch;
    }
    __syncthreads();

    int i = blockIdx.x;
    int sub = tid & 7;        // 8 lanes per row
    int jrow = tid >> 3;      // 32 rows per round
    for (int rr = 0; rr < 16; rr++) {
        int j = rr * 32 + jrow;
        const float4* zp = (const float4*)(z + ((size_t)i * 512 + j) * 128 + sub * 16);
        float s1 = 0.f, s2 = 0.f;
        float a[8] = {0.f,0.f,0.f,0.f,0.f,0.f,0.f,0.f};
        #pragma unroll
        for (int q = 0; q < 4; q++) {
            float4 f = zp[q];
            float xs[4] = {f.x, f.y, f.z, f.w};
            #pragma unroll
            for (int t = 0; t < 4; t++) {
                float x = xs[t];
                s1 += x; s2 += x * x;
                #pragma unroll
                for (int h = 0; h < 8; h++) a[h] += x * WW[h][sub * 16 + q * 4 + t];
            }
        }
        #pragma unroll
        for (int off = 1; off < 8; off <<= 1) {
            s1 += __shfl_xor(s1, off);
            s2 += __shfl_xor(s2, off);
            #pragma unroll
            for (int h = 0; h < 8; h++) a[h] += __shfl_xor(a[h], off);
        }
        if (sub == 0) {
            float mu  = s1 * (1.0f / 128.0f);
            float var = s2 * (1.0f / 128.0f) - mu * mu;
            float inv = rsqrtf(var + 1e-5f);
            float mv  = mask[(size_t)i * 512 + j];
            float madd = (1.0f - mv) * (-1000000.0f);
            #pragma unroll
            for (int h = 0; h < 8; h++)
                LG[h][j] = inv * (a[h] - mu * Ch[h]) + Bh[h] + madd;
        }
    }
    __syncthreads();

    // wave wv handles heads 2*wv and 2*wv+1: in-wave reduce, zero barriers
    #pragma unroll
    for (int hh = 0; hh < 2; hh++) {
        int h = wv * 2 + hh;
        float l[8];
        float mx = -1e30f;
        #pragma unroll
        for (int q = 0; q < 8; q++) {
            l[q] = LG[h][lane + q * 64];
            mx = fmaxf(mx, l[q]);
        }
        mx = wave_max(mx);
        float s = 0.f;
        #pragma unroll
        for (int q = 0; q < 8; q++) {
            l[q] = __expf(l[q] - mx);
            s += l[q];
        }
        s = wave_sum(s);
        float rs = 1.0f / s;
        size_t base = ((size_t)h * 512 + i) * 512;
        #pragma unroll
        for (int q = 0; q < 8; q++)
            wout[base + lane + q * 64] = (_Float16)(l[q] * rs);
    }
}

// ---------------- Kernel 3: o_h = w_h @ vt_h, gate-multiply fused, coalesced RMW of g
// grid (64 c-tiles, 4 i-tiles, 8 heads); operands SWAPPED (af=vt rows n, bf=w rows i)
// 2-phase double-buffered pipeline: STAGE(t+1) hoisted above compute(t),
// single __syncthreads per K-step.
__global__ __launch_bounds__(256) void k_pav(
    const _Float16* __restrict__ wgt, const _Float16* __restrict__ vt,
    _Float16* __restrict__ g)
{
    __shared__ __align__(16) _Float16 lds[2 * 2 * 128 * 64];  // [buf][{A,B}][128][64] = 64 KiB
    int h = blockIdx.z;
    int i0 = blockIdx.y * 128;
    int c0 = blockIdx.x * 128;
    const _Float16* A = wgt + (size_t)h * 512 * 512;
    const _Float16* B = vt  + (size_t)h * 8192 * 512;
    int tid = threadIdx.x;
    int lane = tid & 63, wv = tid >> 6;
    int mrow0 = (wv & 1) * 64, ncol0 = (wv >> 1) * 64;
    int quad = lane >> 4, lc = lane & 15;

    // gl_lds addressing: lane covers row (lane>>3) within its 8-row group;
    // pre-swizzled source chunk = (lane&7) ^ (lane>>3)  (row group start is 8-aligned)
    int rsub = lane >> 3;
    int csw  = ((lane & 7) ^ rsub) * 8;   // halves offset within row

    const _Float16* Ag = A + (size_t)(i0 + wv * 32 + rsub) * 512 + csw;
    const _Float16* Bg = B + (size_t)(c0 + wv * 32 + rsub) * 512 + csw;

    f32x4 acc[4][4];
    #pragma unroll
    for (int mt = 0; mt < 4; mt++)
        #pragma unroll
        for (int nt = 0; nt < 4; nt++) { f32x4 z4 = {0.f,0.f,0.f,0.f}; acc[mt][nt] = z4; }

    // wave wv stages rows [wv*32, wv*32+32) of both operands: 4x 1KB DMA each
    auto stage = [&](int buf, int kb) {
        _Float16* Als = lds + buf * (2 * 128 * 64);
        _Float16* Bls = Als + 128 * 64;
        #pragma unroll
        for (int t = 0; t < 4; t++) {
            int r = wv * 32 + t * 8;   // wave-uniform LDS row start
            async16(&Als[r * 64], Ag + (size_t)(t * 8) * 512 + kb);
            async16(&Bls[r * 64], Bg + (size_t)(t * 8) * 512 + kb);
        }
    };

    stage(0, 0);
    __syncthreads();   // drain prologue DMAs (one exposed latency, once)

    int cur = 0;
    for (int kb = 0; kb < 512; kb += 64) {
        if (kb + 64 < 512) stage(cur ^ 1, kb + 64);   // prefetch next tile

        const _Float16* Al = lds + cur * (2 * 128 * 64);
        const _Float16* Bl = Al + 128 * 64;
        #pragma unroll
        for (int kk = 0; kk < 2; kk++) {
            f16x8 af[4], bf[4];
            #pragma unroll
            for (int mt = 0; mt < 4; mt++) {
                int r = mrow0 + mt * 16 + lc;
                af[mt] = *(const f16x8*)&Bl[r * 64 + (((kk * 4 + quad) ^ (r & 7)) << 3)];  // vt rows (n)
            }
            #pragma unroll
            for (int nt = 0; nt < 4; nt++) {
                int r = ncol0 + nt * 16 + lc;
                bf[nt] = *(const f16x8*)&Al[r * 64 + (((kk * 4 + quad) ^ (r & 7)) << 3)];  // w rows (i)
            }
            #pragma unroll
            for (int mt = 0; mt < 4; mt++)
                #pragma unroll
                for (int nt = 0; nt < 4; nt++)
                    acc[mt][nt] = __builtin_amdgcn_mfma_f32_16x16x32_f16(af[mt], bf[nt], acc[mt][nt], 0, 0, 0);
        }

        __syncthreads();
        cur ^= 1;
    }

    // stage C^T into LDS: T[i_local][n_local] reusing buffer 0
    #pragma unroll
    for (int mt = 0; mt < 4; mt++) {
        int yd = mrow0 + mt * 16 + quad * 4;      // n_local
        #pragma unroll
        for (int nt = 0; nt < 4; nt++) {
            int xd = ncol0 + nt * 16 + lc;        // i_local
            h4u pk;
            #pragma unroll
            for (int t = 0; t < 4; t++) pk.h[t] = (_Float16)acc[mt][nt][t];
            *(ushort4*)&lds[xd * 136 + yd] = pk.u;
        }
    }
    __syncthreads();

    // coalesced gate-RMW writeout: og = g * o (in place over g)
    #pragma unroll
    for (int p = 0; p < 8; p++) {
        int id = p * 256 + tid;
        int il = id >> 4;          // i_local
        int ch = id & 15;          // 8 n per chunk
        int ng = c0 + ch * 8;
        int sj = ng >> 5, e = ng & 31;
        size_t base = ((size_t)sj * 512 + i0 + il) * HC + h * 32 + e;
        h8u ov, gv, res;
        ov.u = *(const uint4*)&lds[il * 136 + ch * 8];
        gv.u = *(const uint4*)&g[base];
        #pragma unroll
        for (int t = 0; t < 8; t++) res.h[t] = (_Float16)((float)ov.h[t] * (float)gv.h[t]);
        *(uint4*)&g[base] = res.u;
    }
}

// ---------------- Kernel 4: out = og @ Wo^T  (131072x256 @ 256x64), fp32 out
// operands swapped (af=Wo rows c, bf=og rows r) -> b128 LDS epilogue, coalesced stores
__global__ __launch_bounds__(256) void k_out(
    const _Float16* __restrict__ og, const float* __restrict__ Wo,
    float* __restrict__ out)
{
    __shared__ __align__(16) char smem[34816];
    _Float16* Blds = (_Float16*)smem;      // 64 x 264
    float* Tf = (float*)smem;              // 128 x 68
    int tid = threadIdx.x;
    int lane = tid & 63, wv = tid >> 6;
    int r0 = blockIdx.x * 128;

    {
        const float4* src = (const float4*)(Wo + (size_t)(tid >> 2) * 256 + (tid & 3) * 64);
        #pragma unroll
        for (int q8 = 0; q8 < 8; q8++) {
            float4 w0 = src[q8*2], w1 = src[q8*2+1];
            float wf[8] = {w0.x,w0.y,w0.z,w0.w,w1.x,w1.y,w1.z,w1.w};
            f16x8 p;
            #pragma unroll
            for (int t = 0; t < 8; t++) p[t] = (_Float16)wf[t];
            *(f16x8*)&Blds[(tid >> 2) * 264 + (tid & 3) * 64 + q8 * 8] = p;
        }
    }
    __syncthreads();

    int quad = lane >> 4, lc = lane & 15;
    f32x4 acc[4][2];   // [c-tiles][r-tiles]
    #pragma unroll
    for (int ct = 0; ct < 4; ct++)
        #pragma unroll
        for (int rt = 0; rt < 2; rt++) { f32x4 z4 = {0.f,0.f,0.f,0.f}; acc[ct][rt] = z4; }

    for (int kb = 0; kb < 256; kb += 32) {
        int kf = kb + quad * 8;
        f16x8 bf[2];
        #pragma unroll
        for (int rt = 0; rt < 2; rt++) {
            int row = r0 + wv * 32 + rt * 16 + lc;
            bf[rt] = *(const f16x8*)(og + (size_t)row * HC + kf);
        }
        f16x8 af[4];
        #pragma unroll
        for (int ct = 0; ct < 4; ct++)
            af[ct] = *(const f16x8*)&Blds[(ct * 16 + lc) * 264 + kf];
        #pragma unroll
        for (int ct = 0; ct < 4; ct++)
            #pragma unroll
            for (int rt = 0; rt < 2; rt++)
                acc[ct][rt] = __builtin_amdgcn_mfma_f32_16x16x32_f16(af[ct], bf[rt], acc[ct][rt], 0, 0, 0);
    }

    __syncthreads();
    // T[r_local][c], 4-consecutive c per thread -> b128 LDS write
    #pragma unroll
    for (int ct = 0; ct < 4; ct++) {
        int cd = ct * 16 + quad * 4;
        #pragma unroll
        for (int rt = 0; rt < 2; rt++) {
            int rd = wv * 32 + rt * 16 + lc;
            *(f32x4*)&Tf[rd * 68 + cd] = acc[ct][rt];
        }
    }
    __syncthreads();

    #pragma unroll
    for (int p = 0; p < 8; p++) {
        int id = p * 256 + tid;
        int rl = id >> 4;          // r_local
        int ch = id & 15;          // 4 f32 per chunk
        uint4 v = *(const uint4*)&Tf[rl * 68 + ch * 4];
        *(uint4*)&out[(size_t)(r0 + rl) * 64 + ch * 4] = v;
    }
}

extern "C" void kernel_launch(void* const* d_in, const int* in_sizes, int n_in,
                              void* d_out, int out_size, void* d_ws, size_t ws_size,
                              hipStream_t stream) {
    const float* m    = (const float*)d_in[0];
    const float* z    = (const float*)d_in[1];
    const float* mask = (const float*)d_in[2];
    const float* lnmw = (const float*)d_in[3];
    const float* lnmb = (const float*)d_in[4];
    const float* lnzw = (const float*)d_in[5];
    const float* lnzb = (const float*)d_in[6];
    const float* Wm   = (const float*)d_in[7];
    const float* Wg   = (const float*)d_in[8];
    const float* Wz   = (const float*)d_in[9];
    const float* Wo   = (const float*)d_in[10];
    float* out = (float*)d_out;

    char* ws = (char*)d_ws;
    _Float16* vt = (_Float16*)ws;                 // 64 MiB  [k_vg -> k_pav]
    _Float16* g  = (_Float16*)(ws + 67108864);    // 64 MiB  [k_vg -> k_pav(in-place og) -> k_out]
    // d_out (33.5 MB) as scratch: w at +0 (4 MiB), Wf16 at +8 MiB (64 KB);
    // both dead before k_out writes out.
    _Float16* w   = (_Float16*)d_out;
    _Float16* Wf  = (_Float16*)((char*)d_out + 8388608);
    (void)in_sizes; (void)n_in; (void)out_size; (void)ws_size;

    k_wcvt<<<32, 256, 0, stream>>>(Wm, Wg, Wf);
    k_vg<<<1024, 256, 0, stream>>>(m, lnmw, lnmb, Wf, vt, g);
    k_bias_softmax<<<512, 256, 0, stream>>>(z, mask, lnzw, lnzb, Wz, w);
    k_pav<<<dim3(64, 4, 8), 256, 0, stream>>>(w, vt, g);
    k_out<<<1024, 256, 0, stream>>>(g, Wo, out);
}